// Round 1
// baseline (1493.617 us; speedup 1.0000x reference)
//
#include <hip/hip_runtime.h>
#include <stdint.h>
#include <stddef.h>

#define FT_IN 41024
#define KHALF 256
#define BATCH 8192
#define NKT 641          // 41024 / 64 K-tiles

typedef __attribute__((ext_vector_type(8))) short short8;
typedef __attribute__((ext_vector_type(4))) short short4v;
typedef __attribute__((ext_vector_type(4))) float f32x4;

typedef const __attribute__((address_space(1))) uint32_t* gas1_t;
typedef __attribute__((address_space(3))) uint32_t* las3_t;

// fp32 -> bf16 with round-to-nearest-even (bit trick; inputs are clean finite values)
__device__ __forceinline__ unsigned short f2bf(float f) {
  union { float f; uint32_t u; } x; x.f = f;
  uint32_t u = x.u + 0x7FFFu + ((x.u >> 16) & 1u);
  return (unsigned short)(u >> 16);
}

// D = A*B + C, 16x16x32 bf16. Inline asm keeps us independent of the builtin's
// vector-element type (short8 vs bf16x8) across ROCm versions.
#define MFMA16(acc, a, b) \
  asm("v_mfma_f32_16x16x32_bf16 %0, %1, %2, %0" : "+v"(acc) : "v"(a), "v"(b))

// ---------------- kernel 1: ft_w fp32 -> bf16 ----------------
__global__ void wprep_kernel(const float* __restrict__ w,
                             unsigned short* __restrict__ o, int n4) {
  int i = blockIdx.x * blockDim.x + threadIdx.x;
  int stride = gridDim.x * blockDim.x;
  for (; i < n4; i += stride) {
    f32x4 v = ((const f32x4*)w)[i];
    short4v b;
    b.x = (short)f2bf(v.x); b.y = (short)f2bf(v.y);
    b.z = (short)f2bf(v.z); b.w = (short)f2bf(v.w);
    ((short4v*)o)[i] = b;
  }
}

// ---------------- kernel 2: feature-transform GEMM ----------------
// grid: 64 rowblocks x 2 colblocks x 2 sets x KS kchunks; block 256 (4 waves)
// per-WG tile: 128 rows x 128 cols, BK=64. A: fp32 global -> cvt -> LDS bf16
// (XOR-swizzled). W: bf16 global -> global_load_lds (source pre-swizzled),
// double-buffered. Output: raw partial sums, transposed [kc][set][col][row].
__global__ __launch_bounds__(256) void ftgemm_kernel(
    const float* __restrict__ f1g, const float* __restrict__ f2g,
    const unsigned short* __restrict__ wb,
    float* __restrict__ part, int KS) {
  __shared__ alignas(16) char sA[16384];
  __shared__ alignas(16) char sW[2][16384];

  int bid = blockIdx.x;
  const int rb = bid & 63; bid >>= 6;
  const int cb = bid & 1;  bid >>= 1;
  const int st = bid & 1;  bid >>= 1;
  const int ks = bid;

  const int kt0 = (ks * NKT) / KS;
  const int kt1 = ((ks + 1) * NKT) / KS;

  const int tid  = (int)threadIdx.x;
  const int lane = tid & 63;
  const int wv   = tid >> 6;
  const int wr   = (wv >> 1) << 6;   // wave row offset: 0 / 64
  const int wc   = (wv & 1) << 6;    // wave col offset: 0 / 64
  const int r16  = lane & 15;
  const int hi   = lane >> 4;

  const float* F = (st ? f2g : f1g) + (size_t)rb * (128ull * FT_IN);

  // A staging map: thread covers rows (i*16 + tid>>4), k-chunk (tid&15)*4
  const int arow = tid >> 4;
  const int akc  = tid & 15;
  const float* aptr = F + (size_t)arow * FT_IN + (size_t)kt0 * 64 + akc * 4;

  // W staging map (global_load_lds, linear LDS dest): chunk c = i*256+tid,
  // row = c>>3, kc = c&7; source chunk XOR-pre-swizzled so reads can swizzle.
  const int wrow = tid >> 3;               // +32 per i; (row&7) invariant in i
  const int wkc  = tid & 7;
  const int wkcs = wkc ^ (wrow & 7);
  const unsigned short* wptr =
      wb + (size_t)(cb * 128 + wrow) * FT_IN + (size_t)kt0 * 64;

  f32x4 areg[8];
  f32x4 acc[4][4];
  const f32x4 fzero = {0.f, 0.f, 0.f, 0.f};
  #pragma unroll
  for (int m = 0; m < 4; ++m)
    #pragma unroll
    for (int n = 0; n < 4; ++n) acc[m][n] = fzero;

  // prologue: A regs + W glds for tile kt0
  #pragma unroll
  for (int i = 0; i < 8; ++i)
    areg[i] = *(const f32x4*)(aptr + (size_t)i * (16ull * FT_IN));
  #pragma unroll
  for (int i = 0; i < 4; ++i) {
    const unsigned short* g = wptr + (size_t)i * (32ull * FT_IN) + wkcs * 8;
    __builtin_amdgcn_global_load_lds((gas1_t)g,
        (las3_t)&sW[0][(i * 256 + tid) * 16], 16, 0, 0);
  }

  int buf = 0;
  for (int kt = kt0; kt < kt1; ++kt) {
    // convert + store A tile (swizzle: byte ^= (row&7)<<4)
    #pragma unroll
    for (int i = 0; i < 8; ++i) {
      const int row = i * 16 + arow;
      f32x4 v = areg[i];
      short4v b;
      b.x = (short)f2bf(v.x); b.y = (short)f2bf(v.y);
      b.z = (short)f2bf(v.z); b.w = (short)f2bf(v.w);
      *(short4v*)(sA + row * 128 + ((akc * 8) ^ ((row & 7) << 4))) = b;
    }
    __syncthreads();   // sA ready; glds into sW[buf] drained

    if (kt + 1 < kt1) {  // prefetch next tile (latency hides under MFMA)
      const int d = kt + 1 - kt0;
      const float* ap = aptr + d * 64;
      #pragma unroll
      for (int i = 0; i < 8; ++i)
        areg[i] = *(const f32x4*)(ap + (size_t)i * (16ull * FT_IN));
      const unsigned short* wp = wptr + d * 64;
      #pragma unroll
      for (int i = 0; i < 4; ++i) {
        const unsigned short* g = wp + (size_t)i * (32ull * FT_IN) + wkcs * 8;
        __builtin_amdgcn_global_load_lds((gas1_t)g,
            (las3_t)&sW[buf ^ 1][(i * 256 + tid) * 16], 16, 0, 0);
      }
    }

    const char* sWb = sW[buf];
    const int swz = (r16 & 7) << 4;
    #pragma unroll
    for (int k2 = 0; k2 < 2; ++k2) {
      const int ko = (k2 * 64 + hi * 16) ^ swz;
      short8 av[4], bv[4];
      #pragma unroll
      for (int m = 0; m < 4; ++m)
        av[m] = *(const short8*)(sA + (wr + m * 16 + r16) * 128 + ko);
      #pragma unroll
      for (int n = 0; n < 4; ++n)
        bv[n] = *(const short8*)(sWb + (wc + n * 16 + r16) * 128 + ko);
      #pragma unroll
      for (int m = 0; m < 4; ++m)
        #pragma unroll
        for (int n = 0; n < 4; ++n)
          MFMA16(acc[m][n], av[m], bv[n]);
    }
    __syncthreads();
    buf ^= 1;
  }

  // epilogue: raw partials, transposed [ks*2+set][col][row]; D frag:
  // col = lane&15, row = (lane>>4)*4 + reg (4 regs = 4 consecutive rows)
  float* pb = part + (size_t)(ks * 2 + st) * (KHALF * (size_t)BATCH);
  const int growb = rb * 128 + wr + hi * 4;
  const int gcolb = cb * 128 + wc + r16;
  #pragma unroll
  for (int n = 0; n < 4; ++n)
    #pragma unroll
    for (int m = 0; m < 4; ++m)
      *(f32x4*)(pb + (size_t)(gcolb + n * 16) * BATCH + (growb + m * 16)) =
          acc[m][n];
}

// ---------------- kernel 3: tail MLP ----------------
// thread t = one batch row. Partials are [col][row]-transposed -> coalesced.
__global__ __launch_bounds__(256) void tail_kernel(
    const float* __restrict__ part,
    const float* __restrict__ ftb, const float* __restrict__ h1w,
    const float* __restrict__ h1b, const float* __restrict__ h2w,
    const float* __restrict__ h2b, const float* __restrict__ outw,
    const float* __restrict__ outb, float* __restrict__ out, int KS) {
  __shared__ float sh1t[512 * 32];   // h1_w transposed [col][j]
  __shared__ float sh2[32 * 32];
  __shared__ float sow[32];
  __shared__ float sh1b[32];
  __shared__ float sh2b[32];
  __shared__ float sftb[256];
  __shared__ float sob[1];

  const int tid = (int)threadIdx.x;
  for (int i = tid; i < 512 * 32; i += 256)
    sh1t[(i & 511) * 32 + (i >> 9)] = h1w[i];
  for (int i = tid; i < 1024; i += 256) sh2[i] = h2w[i];
  if (tid < 32) { sow[tid] = outw[tid]; sh1b[tid] = h1b[tid]; sh2b[tid] = h2b[tid]; }
  sftb[tid] = ftb[tid];
  if (tid == 0) sob[0] = outb[0];
  __syncthreads();

  const int t = (int)blockIdx.x * 256 + tid;
  float a1[32];
  #pragma unroll
  for (int j = 0; j < 32; ++j) a1[j] = sh1b[j];

  for (int s2 = 0; s2 < 2; ++s2) {
    const float* pbase = part + (size_t)s2 * (KHALF * (size_t)BATCH) + t;
    for (int c = 0; c < 256; ++c) {
      float v = sftb[c];
      const float* p = pbase + (size_t)c * BATCH;
      for (int kq = 0; kq < KS; ++kq)
        v += p[(size_t)kq * (2ull * KHALF * BATCH)];
      v = fminf(fmaxf(v, 0.f), 1.f);
      const f32x4* wr4 = (const f32x4*)(sh1t + (s2 * 256 + c) * 32);
      #pragma unroll
      for (int q = 0; q < 8; ++q) {
        f32x4 wv = wr4[q];
        a1[q * 4 + 0] += v * wv.x; a1[q * 4 + 1] += v * wv.y;
        a1[q * 4 + 2] += v * wv.z; a1[q * 4 + 3] += v * wv.w;
      }
    }
  }
  #pragma unroll
  for (int j = 0; j < 32; ++j) a1[j] = fminf(fmaxf(a1[j], 0.f), 1.f);

  float a2[32];
  #pragma unroll
  for (int j = 0; j < 32; ++j) {
    float x = sh2b[j];
    const f32x4* w2 = (const f32x4*)(sh2 + j * 32);
    #pragma unroll
    for (int q = 0; q < 8; ++q) {
      f32x4 wv = w2[q];
      x += a1[q * 4 + 0] * wv.x + a1[q * 4 + 1] * wv.y +
           a1[q * 4 + 2] * wv.z + a1[q * 4 + 3] * wv.w;
    }
    a2[j] = fminf(fmaxf(x, 0.f), 1.f);
  }
  float o = sob[0];
  #pragma unroll
  for (int j = 0; j < 32; ++j) o += a2[j] * sow[j];
  out[t] = o;
}

// ---------------- launch ----------------
extern "C" void kernel_launch(void* const* d_in, const int* in_sizes, int n_in,
                              void* d_out, int out_size, void* d_ws, size_t ws_size,
                              hipStream_t stream) {
  const float* f1   = (const float*)d_in[0];
  const float* f2   = (const float*)d_in[1];
  const float* ftw  = (const float*)d_in[2];
  const float* ftb  = (const float*)d_in[3];
  const float* h1w  = (const float*)d_in[4];
  const float* h1b  = (const float*)d_in[5];
  const float* h2w  = (const float*)d_in[6];
  const float* h2b  = (const float*)d_in[7];
  const float* outw = (const float*)d_in[8];
  const float* outb = (const float*)d_in[9];
  float* out = (float*)d_out;

  unsigned short* wb = (unsigned short*)d_ws;
  const size_t woff = (size_t)KHALF * FT_IN * 2;            // 21,004,288 B
  float* part = (float*)((char*)d_ws + woff);
  const size_t per = 2ull * KHALF * BATCH * 4;              // 16,777,216 B / kchunk
  int KS = 1;
  if (ws_size > woff + per) {
    size_t k = (ws_size - woff) / per;
    KS = (int)(k > 4 ? 4 : k);
  }
  if (KS < 1) KS = 1;

  wprep_kernel<<<2048, 256, 0, stream>>>(ftw, wb, (KHALF * FT_IN) / 4);
  ftgemm_kernel<<<dim3(64 * 2 * 2 * KS), 256, 0, stream>>>(f1, f2, wb, part, KS);
  tail_kernel<<<BATCH / 256, 256, 0, stream>>>(part, ftb, h1w, h1b, h2w, h2b,
                                               outw, outb, out, KS);
}

// Round 3
// 817.911 us; speedup vs baseline: 1.8261x; 1.8261x over previous
//
#include <hip/hip_runtime.h>
#include <stdint.h>
#include <stddef.h>

#define FT_IN 41024
#define KHALF 256
#define BATCH 8192
#define NKT 641          // 41024 / 64 K-tiles

typedef __attribute__((ext_vector_type(8))) short short8;
typedef __attribute__((ext_vector_type(4))) short short4v;
typedef __attribute__((ext_vector_type(4))) float f32x4;
typedef __attribute__((ext_vector_type(2))) uint32_t u32x2;

typedef const __attribute__((address_space(1))) uint32_t* gas1_t;
typedef __attribute__((address_space(3))) uint32_t* las3_t;

// fp32 -> bf16 RNE (bit trick) — used only in the small wprep pass
__device__ __forceinline__ unsigned short f2bf(float f) {
  union { float f; uint32_t u; } x; x.f = f;
  uint32_t u = x.u + 0x7FFFu + ((x.u >> 16) & 1u);
  return (unsigned short)(u >> 16);
}

#define MFMA16(acc, a, b) \
  asm("v_mfma_f32_16x16x32_bf16 %0, %1, %2, %0" : "+v"(acc) : "v"(a), "v"(b))

// packed fp32x2 -> bf16x2 (RNE), lo -> bits[15:0]
#define CVTPK(dst, lo, hi) \
  asm("v_cvt_pk_bf16_f32 %0, %1, %2" : "=v"(dst) : "v"(lo), "v"(hi))

// ---------------- kernel 1: ft_w fp32 -> bf16 ----------------
__global__ void wprep_kernel(const float* __restrict__ w,
                             unsigned short* __restrict__ o, int n4) {
  int i = blockIdx.x * blockDim.x + threadIdx.x;
  int stride = gridDim.x * blockDim.x;
  for (; i < n4; i += stride) {
    f32x4 v = ((const f32x4*)w)[i];
    short4v b;
    b.x = (short)f2bf(v.x); b.y = (short)f2bf(v.y);
    b.z = (short)f2bf(v.z); b.w = (short)f2bf(v.w);
    ((short4v*)o)[i] = b;
  }
}

// ---------------- kernel 2: feature-transform GEMM ----------------
// grid: 64 rowblocks x 2 colblocks x 2 sets x KS kchunks; block 256 (4 waves)
// per-WG tile: 128 rows x 128 cols, BK=64. A: fp32 global -> v_cvt_pk_bf16 ->
// LDS bf16 (XOR-swizzled). W: bf16 global -> global_load_lds (source
// pre-swizzled), double-buffered. Output: raw partials [kc*2+set][col][row].
__global__ __launch_bounds__(256) void ftgemm_kernel(
    const float* __restrict__ f1g, const float* __restrict__ f2g,
    const unsigned short* __restrict__ wb,
    float* __restrict__ part, int KS) {
  __shared__ alignas(16) char sA[16384];
  __shared__ alignas(16) char sW[2][16384];

  int bid = blockIdx.x;
  const int rb = bid & 63; bid >>= 6;
  const int cb = bid & 1;  bid >>= 1;
  const int st = bid & 1;  bid >>= 1;
  const int ks = bid;

  const int kt0 = (ks * NKT) / KS;
  const int kt1 = ((ks + 1) * NKT) / KS;

  const int tid  = (int)threadIdx.x;
  const int lane = tid & 63;
  const int wv   = tid >> 6;
  const int wr   = (wv >> 1) << 6;   // wave row offset: 0 / 64
  const int wc   = (wv & 1) << 6;    // wave col offset: 0 / 64
  const int r16  = lane & 15;
  const int hi   = lane >> 4;

  const float* F = (st ? f2g : f1g) + (size_t)rb * (128ull * FT_IN);

  // A staging map: thread covers rows (i*16 + tid>>4), k-chunk (tid&15)*4
  const int arow = tid >> 4;
  const int akc  = tid & 15;
  const float* aptr = F + (size_t)arow * FT_IN + (size_t)kt0 * 64 + akc * 4;

  // W staging map (global_load_lds, linear LDS dest): chunk c = i*256+tid,
  // row = c>>3, kc = c&7; source chunk XOR-pre-swizzled so reads can swizzle.
  const int wrow = tid >> 3;               // +32 per i; (row&7) invariant in i
  const int wkc  = tid & 7;
  const int wkcs = wkc ^ (wrow & 7);
  const unsigned short* wptr =
      wb + (size_t)(cb * 128 + wrow) * FT_IN + (size_t)kt0 * 64;

  f32x4 areg[8];
  f32x4 acc[4][4];
  const f32x4 fzero = {0.f, 0.f, 0.f, 0.f};
  #pragma unroll
  for (int m = 0; m < 4; ++m)
    #pragma unroll
    for (int n = 0; n < 4; ++n) acc[m][n] = fzero;

  // prologue: A regs + W glds for tile kt0
  #pragma unroll
  for (int i = 0; i < 8; ++i)
    areg[i] = *(const f32x4*)(aptr + (size_t)i * (16ull * FT_IN));
  #pragma unroll
  for (int i = 0; i < 4; ++i) {
    const unsigned short* g = wptr + (size_t)i * (32ull * FT_IN) + wkcs * 8;
    __builtin_amdgcn_global_load_lds((gas1_t)g,
        (las3_t)&sW[0][(i * 256 + tid) * 16], 16, 0, 0);
  }

  int buf = 0;
  for (int kt = kt0; kt < kt1; ++kt) {
    // convert + store A tile (swizzle: byte ^= (row&7)<<4)
    #pragma unroll
    for (int i = 0; i < 8; ++i) {
      const int row = i * 16 + arow;
      f32x4 v = areg[i];
      uint32_t b0, b1;
      CVTPK(b0, v.x, v.y);
      CVTPK(b1, v.z, v.w);
      u32x2 b; b.x = b0; b.y = b1;
      *(u32x2*)(sA + row * 128 + ((akc * 8) ^ ((row & 7) << 4))) = b;
    }
    __syncthreads();   // sA ready; glds into sW[buf] drained

    if (kt + 1 < kt1) {  // prefetch next tile (latency hides under MFMA)
      const int d = kt + 1 - kt0;
      const float* ap = aptr + d * 64;
      #pragma unroll
      for (int i = 0; i < 8; ++i)
        areg[i] = *(const f32x4*)(ap + (size_t)i * (16ull * FT_IN));
      const unsigned short* wp = wptr + d * 64;
      #pragma unroll
      for (int i = 0; i < 4; ++i) {
        const unsigned short* g = wp + (size_t)i * (32ull * FT_IN) + wkcs * 8;
        __builtin_amdgcn_global_load_lds((gas1_t)g,
            (las3_t)&sW[buf ^ 1][(i * 256 + tid) * 16], 16, 0, 0);
      }
    }

    const char* sWb = sW[buf];
    const int swz = (r16 & 7) << 4;
    #pragma unroll
    for (int k2 = 0; k2 < 2; ++k2) {
      const int ko = (k2 * 64 + hi * 16) ^ swz;
      short8 av[4], bv[4];
      #pragma unroll
      for (int m = 0; m < 4; ++m)
        av[m] = *(const short8*)(sA + (wr + m * 16 + r16) * 128 + ko);
      #pragma unroll
      for (int n = 0; n < 4; ++n)
        bv[n] = *(const short8*)(sWb + (wc + n * 16 + r16) * 128 + ko);
      #pragma unroll
      for (int m = 0; m < 4; ++m)
        #pragma unroll
        for (int n = 0; n < 4; ++n)
          MFMA16(acc[m][n], av[m], bv[n]);
    }
    __syncthreads();
    buf ^= 1;
  }

  // epilogue: raw partials, transposed [ks*2+set][col][row]; D frag:
  // col = lane&15, row = (lane>>4)*4 + reg (4 regs = 4 consecutive rows)
  float* pb = part + (size_t)(ks * 2 + st) * (KHALF * (size_t)BATCH);
  const int growb = rb * 128 + wr + hi * 4;
  const int gcolb = cb * 128 + wc + r16;
  #pragma unroll
  for (int n = 0; n < 4; ++n)
    #pragma unroll
    for (int m = 0; m < 4; ++m)
      *(f32x4*)(pb + (size_t)(gcolb + n * 16) * BATCH + (growb + m * 16)) =
          acc[m][n];
}

// ---------------- kernel 3: tail MLP ----------------
// 256 blocks x 32 rows. Thread (r = tid&31, cg = tid>>5): row r, 64 cols
// [cg*64, cg*64+64). a1-partials reduced across the 8 col-groups via LDS.
__global__ __launch_bounds__(256) void tail_kernel(
    const float* __restrict__ part,
    const float* __restrict__ ftb, const float* __restrict__ h1w,
    const float* __restrict__ h1b, const float* __restrict__ h2w,
    const float* __restrict__ h2b, const float* __restrict__ outw,
    const float* __restrict__ outb, float* __restrict__ out, int KS) {
  __shared__ float sh1t[512 * 36];   // h1_w transposed [c][j], stride 36 (pad)
  __shared__ float sh2[32 * 32];
  __shared__ float sow[32];
  __shared__ float sh1b[32];
  __shared__ float sh2b[32];
  __shared__ float sftb[256];
  __shared__ float sob[1];

  const int tid = (int)threadIdx.x;
  // coalesced global read (c fast), strided LDS write
  for (int i = tid; i < 512 * 32; i += 256) {
    const int j = i >> 9, c = i & 511;
    sh1t[c * 36 + j] = h1w[i];       // h1w[j][c]
  }
  for (int i = tid; i < 1024; i += 256) sh2[i] = h2w[i];
  if (tid < 32) { sow[tid] = outw[tid]; sh1b[tid] = h1b[tid]; sh2b[tid] = h2b[tid]; }
  sftb[tid] = ftb[tid];
  if (tid == 0) sob[0] = outb[0];
  __syncthreads();

  const int r  = tid & 31;
  const int cg = tid >> 5;
  const int t  = (int)blockIdx.x * 32 + r;   // global batch row

  float a1p[32];
  #pragma unroll
  for (int j = 0; j < 32; ++j) a1p[j] = 0.f;

  for (int ci = 0; ci < 64; ++ci) {
    const int c   = cg * 64 + ci;
    const int set = c >> 8;
    const int cs  = c & 255;
    float v = sftb[cs];
    const float* p = part + ((size_t)set * KHALF + cs) * BATCH + t;
    for (int kq = 0; kq < KS; ++kq)
      v += p[(size_t)kq * (2ull * KHALF * BATCH)];
    v = fminf(fmaxf(v, 0.f), 1.f);
    const f32x4* wr4 = (const f32x4*)(sh1t + c * 36);
    #pragma unroll
    for (int q = 0; q < 8; ++q) {
      f32x4 wv = wr4[q];
      a1p[q * 4 + 0] += v * wv.x; a1p[q * 4 + 1] += v * wv.y;
      a1p[q * 4 + 2] += v * wv.z; a1p[q * 4 + 3] += v * wv.w;
    }
  }

  // reduce the 8 col-group partials per row via LDS (reuse sh1t region)
  float* red = sh1t;                  // [8][32][33]
  __syncthreads();
  #pragma unroll
  for (int j = 0; j < 32; ++j)
    red[(cg * 32 + r) * 33 + j] = a1p[j];
  __syncthreads();

  if (tid < 32) {
    float a1[32];
    #pragma unroll
    for (int j = 0; j < 32; ++j) a1[j] = sh1b[j];
    for (int g = 0; g < 8; ++g)
      #pragma unroll
      for (int j = 0; j < 32; ++j)
        a1[j] += red[(g * 32 + tid) * 33 + j];
    #pragma unroll
    for (int j = 0; j < 32; ++j) a1[j] = fminf(fmaxf(a1[j], 0.f), 1.f);

    float a2[32];
    #pragma unroll
    for (int j = 0; j < 32; ++j) {
      float x = sh2b[j];
      const f32x4* w2 = (const f32x4*)(sh2 + j * 32);
      #pragma unroll
      for (int q = 0; q < 8; ++q) {
        f32x4 wv = w2[q];
        x += a1[q * 4 + 0] * wv.x + a1[q * 4 + 1] * wv.y +
             a1[q * 4 + 2] * wv.z + a1[q * 4 + 3] * wv.w;
      }
      a2[j] = fminf(fmaxf(x, 0.f), 1.f);
    }
    float o = sob[0];
    #pragma unroll
    for (int j = 0; j < 32; ++j) o += a2[j] * sow[j];
    out[(int)blockIdx.x * 32 + tid] = o;
  }
}

// ---------------- launch ----------------
extern "C" void kernel_launch(void* const* d_in, const int* in_sizes, int n_in,
                              void* d_out, int out_size, void* d_ws, size_t ws_size,
                              hipStream_t stream) {
  const float* f1   = (const float*)d_in[0];
  const float* f2   = (const float*)d_in[1];
  const float* ftw  = (const float*)d_in[2];
  const float* ftb  = (const float*)d_in[3];
  const float* h1w  = (const float*)d_in[4];
  const float* h1b  = (const float*)d_in[5];
  const float* h2w  = (const float*)d_in[6];
  const float* h2b  = (const float*)d_in[7];
  const float* outw = (const float*)d_in[8];
  const float* outb = (const float*)d_in[9];
  float* out = (float*)d_out;

  unsigned short* wb = (unsigned short*)d_ws;
  const size_t woff = (size_t)KHALF * FT_IN * 2;            // 21,004,288 B
  float* part = (float*)((char*)d_ws + woff);
  const size_t per = 2ull * KHALF * BATCH * 4;              // 16,777,216 B / kchunk

  // KS=3 -> 768 WGs = exactly 3 WGs/CU (48 KB LDS) x 256 CUs, one clean round
  int KS = 1;
  if (ws_size >= woff + 3 * per)      KS = 3;
  else if (ws_size >= woff + 2 * per) KS = 2;

  wprep_kernel<<<2048, 256, 0, stream>>>(ftw, wb, (KHALF * FT_IN) / 4);
  ftgemm_kernel<<<dim3(64 * 2 * 2 * KS), 256, 0, stream>>>(f1, f2, wb, part, KS);
  // 32 rows per block -> BATCH/32 = 256 blocks (round-2 bug: was BATCH/256)
  tail_kernel<<<BATCH / 32, 256, 0, stream>>>(part, ftb, h1w, h1b, h2w, h2b,
                                              outw, outb, out, KS);
}

// Round 4
// 664.899 us; speedup vs baseline: 2.2464x; 1.2301x over previous
//
#include <hip/hip_runtime.h>
#include <stdint.h>
#include <stddef.h>

#define FT_IN 41024
#define KHALF 256
#define BATCH 8192
#define NKT 641          // 41024 / 64 K-tiles

typedef __attribute__((ext_vector_type(8))) short short8;
typedef __attribute__((ext_vector_type(4))) short short4v;
typedef __attribute__((ext_vector_type(4))) float f32x4;
typedef __attribute__((ext_vector_type(2))) uint32_t u32x2;

typedef const __attribute__((address_space(1))) uint32_t* gas1_t;
typedef __attribute__((address_space(3))) uint32_t* las3_t;

// fp32 -> bf16 RNE (bit trick) — used only in the small wprep pass
__device__ __forceinline__ unsigned short f2bf(float f) {
  union { float f; uint32_t u; } x; x.f = f;
  uint32_t u = x.u + 0x7FFFu + ((x.u >> 16) & 1u);
  return (unsigned short)(u >> 16);
}

#define MFMA16(acc, a, b) \
  asm("v_mfma_f32_16x16x32_bf16 %0, %1, %2, %0" : "+v"(acc) : "v"(a), "v"(b))

// packed fp32x2 -> bf16x2 (RNE), lo -> bits[15:0]
#define CVTPK(dst, lo, hi) \
  asm("v_cvt_pk_bf16_f32 %0, %1, %2" : "=v"(dst) : "v"(lo), "v"(hi))

// ---------------- kernel 1: ft_w fp32 -> bf16 ----------------
__global__ void wprep_kernel(const float* __restrict__ w,
                             unsigned short* __restrict__ o, int n4) {
  int i = blockIdx.x * blockDim.x + threadIdx.x;
  int stride = gridDim.x * blockDim.x;
  for (; i < n4; i += stride) {
    f32x4 v = ((const f32x4*)w)[i];
    short4v b;
    b.x = (short)f2bf(v.x); b.y = (short)f2bf(v.y);
    b.z = (short)f2bf(v.z); b.w = (short)f2bf(v.w);
    ((short4v*)o)[i] = b;
  }
}

// ---------------- kernel 2: feature-transform GEMM ----------------
// grid: 64 rowblocks x 2 sets x KS kchunks (512 WGs = 2/CU); block 256.
// per-WG tile: 128 rows x 256 cols (FULL col range -> features read ONCE),
// BK=64. A: fp32 global -> v_cvt_pk_bf16 -> LDS (XOR-swizzled). W: bf16
// global -> global_load_lds (source pre-swizzled), double-buffered (2x32KB).
// Waves 2x2: each 64 rows x 128 cols = 4x8 fragments.
__global__ __launch_bounds__(256, 2) void ftgemm_kernel(
    const float* __restrict__ f1g, const float* __restrict__ f2g,
    const unsigned short* __restrict__ wb,
    float* __restrict__ part, int KS) {
  __shared__ alignas(16) char sA[16384];
  __shared__ alignas(16) char sW[2][32768];

  int bid = blockIdx.x;
  const int rb = bid & 63; bid >>= 6;
  const int st = bid & 1;  bid >>= 1;
  const int ks = bid;

  const int kt0 = (ks * NKT) / KS;
  const int kt1 = ((ks + 1) * NKT) / KS;

  const int tid  = (int)threadIdx.x;
  const int lane = tid & 63;
  const int wv   = tid >> 6;
  const int wr   = (wv >> 1) << 6;   // wave row offset: 0 / 64
  const int wc   = (wv & 1) << 7;    // wave col offset: 0 / 128
  const int r16  = lane & 15;
  const int hi   = lane >> 4;

  const float* F = (st ? f2g : f1g) + (size_t)rb * (128ull * FT_IN);

  // A staging: thread covers rows (i*16 + tid>>4), k-chunk (tid&15)*4 floats
  const int arow = tid >> 4;
  const int akc  = tid & 15;
  const float* aptr = F + (size_t)arow * FT_IN + (size_t)kt0 * 64 + akc * 4;

  // W staging (global_load_lds, linear LDS dest): chunk c = i*256+tid,
  // row = c>>3 (i adds 32 rows), kc = c&7; source XOR-pre-swizzled.
  const int wrow = tid >> 3;
  const int wkc  = tid & 7;
  const int wkcs = wkc ^ (wrow & 7);
  const unsigned short* wptr =
      wb + (size_t)wrow * FT_IN + (size_t)kt0 * 64;

  f32x4 areg[8];
  f32x4 acc[4][8];
  const f32x4 fzero = {0.f, 0.f, 0.f, 0.f};
  #pragma unroll
  for (int m = 0; m < 4; ++m)
    #pragma unroll
    for (int n = 0; n < 8; ++n) acc[m][n] = fzero;

  // prologue: A regs + W glds for tile kt0
  #pragma unroll
  for (int i = 0; i < 8; ++i)
    areg[i] = *(const f32x4*)(aptr + (size_t)i * (16ull * FT_IN));
  #pragma unroll
  for (int i = 0; i < 8; ++i) {
    const unsigned short* g = wptr + (size_t)i * (32ull * FT_IN) + wkcs * 8;
    __builtin_amdgcn_global_load_lds((gas1_t)g,
        (las3_t)&sW[0][(i * 256 + tid) * 16], 16, 0, 0);
  }

  int buf = 0;
  for (int kt = kt0; kt < kt1; ++kt) {
    // convert + store A tile (swizzle: byte ^= (row&7)<<4)
    #pragma unroll
    for (int i = 0; i < 8; ++i) {
      const int row = i * 16 + arow;
      f32x4 v = areg[i];
      uint32_t b0, b1;
      CVTPK(b0, v.x, v.y);
      CVTPK(b1, v.z, v.w);
      u32x2 b; b.x = b0; b.y = b1;
      *(u32x2*)(sA + row * 128 + ((akc * 8) ^ ((row & 7) << 4))) = b;
    }
    __syncthreads();   // sA ready; glds into sW[buf] drained

    if (kt + 1 < kt1) {  // prefetch next tile (hides under MFMA phase)
      const int d = kt + 1 - kt0;
      const float* ap = aptr + d * 64;
      #pragma unroll
      for (int i = 0; i < 8; ++i)
        areg[i] = *(const f32x4*)(ap + (size_t)i * (16ull * FT_IN));
      const unsigned short* wp = wptr + d * 64;
      #pragma unroll
      for (int i = 0; i < 8; ++i) {
        const unsigned short* g = wp + (size_t)i * (32ull * FT_IN) + wkcs * 8;
        __builtin_amdgcn_global_load_lds((gas1_t)g,
            (las3_t)&sW[buf ^ 1][(i * 256 + tid) * 16], 16, 0, 0);
      }
    }

    const char* sWb = sW[buf];
    const int swz = (r16 & 7) << 4;
    #pragma unroll
    for (int k2 = 0; k2 < 2; ++k2) {
      const int ko = (k2 * 64 + hi * 16) ^ swz;
      short8 av[4], bv[8];
      #pragma unroll
      for (int m = 0; m < 4; ++m)
        av[m] = *(const short8*)(sA + (wr + m * 16 + r16) * 128 + ko);
      #pragma unroll
      for (int n = 0; n < 8; ++n)
        bv[n] = *(const short8*)(sWb + (wc + n * 16 + r16) * 128 + ko);
      #pragma unroll
      for (int m = 0; m < 4; ++m)
        #pragma unroll
        for (int n = 0; n < 8; ++n)
          MFMA16(acc[m][n], av[m], bv[n]);
    }
    __syncthreads();
    buf ^= 1;
  }

  // epilogue: raw partials [ks*2+set][col][row]; D frag: col = lane&15,
  // row = (lane>>4)*4 + reg (4 regs = 4 consecutive rows -> f32x4 store)
  float* pb = part + (size_t)(ks * 2 + st) * (KHALF * (size_t)BATCH);
  const int growb = rb * 128 + wr + hi * 4;
  const int gcolb = wc + r16;
  #pragma unroll
  for (int n = 0; n < 8; ++n)
    #pragma unroll
    for (int m = 0; m < 4; ++m)
      *(f32x4*)(pb + (size_t)(gcolb + n * 16) * BATCH + (growb + m * 16)) =
          acc[m][n];
}

// ---------------- kernel 3: tail MLP ----------------
// 256 blocks x 32 rows. Thread (r = tid&31, cg = tid>>5): row r, 64 cols
// [cg*64, cg*64+64). a1-partials reduced across the 8 col-groups via LDS.
__global__ __launch_bounds__(256) void tail_kernel(
    const float* __restrict__ part,
    const float* __restrict__ ftb, const float* __restrict__ h1w,
    const float* __restrict__ h1b, const float* __restrict__ h2w,
    const float* __restrict__ h2b, const float* __restrict__ outw,
    const float* __restrict__ outb, float* __restrict__ out, int KS) {
  __shared__ float sh1t[512 * 36];   // h1_w transposed [c][j], stride 36 (pad)
  __shared__ float sh2[32 * 32];
  __shared__ float sow[32];
  __shared__ float sh1b[32];
  __shared__ float sh2b[32];
  __shared__ float sftb[256];
  __shared__ float sob[1];

  const int tid = (int)threadIdx.x;
  // coalesced global read (c fast), strided LDS write
  for (int i = tid; i < 512 * 32; i += 256) {
    const int j = i >> 9, c = i & 511;
    sh1t[c * 36 + j] = h1w[i];       // h1w[j][c]
  }
  for (int i = tid; i < 1024; i += 256) sh2[i] = h2w[i];
  if (tid < 32) { sow[tid] = outw[tid]; sh1b[tid] = h1b[tid]; sh2b[tid] = h2b[tid]; }
  sftb[tid] = ftb[tid];
  if (tid == 0) sob[0] = outb[0];
  __syncthreads();

  const int r  = tid & 31;
  const int cg = tid >> 5;
  const int t  = (int)blockIdx.x * 32 + r;   // global batch row

  float a1p[32];
  #pragma unroll
  for (int j = 0; j < 32; ++j) a1p[j] = 0.f;

  for (int ci = 0; ci < 64; ++ci) {
    const int c   = cg * 64 + ci;
    const int set = c >> 8;
    const int cs  = c & 255;
    float v = sftb[cs];
    const float* p = part + ((size_t)set * KHALF + cs) * BATCH + t;
    for (int kq = 0; kq < KS; ++kq)
      v += p[(size_t)kq * (2ull * KHALF * BATCH)];
    v = fminf(fmaxf(v, 0.f), 1.f);
    const f32x4* wr4 = (const f32x4*)(sh1t + c * 36);
    #pragma unroll
    for (int q = 0; q < 8; ++q) {
      f32x4 wv = wr4[q];
      a1p[q * 4 + 0] += v * wv.x; a1p[q * 4 + 1] += v * wv.y;
      a1p[q * 4 + 2] += v * wv.z; a1p[q * 4 + 3] += v * wv.w;
    }
  }

  // reduce the 8 col-group partials per row via LDS (reuse sh1t region)
  float* red = sh1t;                  // [8][32][33]
  __syncthreads();
  #pragma unroll
  for (int j = 0; j < 32; ++j)
    red[(cg * 32 + r) * 33 + j] = a1p[j];
  __syncthreads();

  if (tid < 32) {
    float a1[32];
    #pragma unroll
    for (int j = 0; j < 32; ++j) a1[j] = sh1b[j];
    for (int g = 0; g < 8; ++g)
      #pragma unroll
      for (int j = 0; j < 32; ++j)
        a1[j] += red[(g * 32 + tid) * 33 + j];
    #pragma unroll
    for (int j = 0; j < 32; ++j) a1[j] = fminf(fmaxf(a1[j], 0.f), 1.f);

    float a2[32];
    #pragma unroll
    for (int j = 0; j < 32; ++j) {
      float x = sh2b[j];
      const f32x4* w2 = (const f32x4*)(sh2 + j * 32);
      #pragma unroll
      for (int q = 0; q < 8; ++q) {
        f32x4 wv = w2[q];
        x += a1[q * 4 + 0] * wv.x + a1[q * 4 + 1] * wv.y +
             a1[q * 4 + 2] * wv.z + a1[q * 4 + 3] * wv.w;
      }
      a2[j] = fminf(fmaxf(x, 0.f), 1.f);
    }
    float o = sob[0];
    #pragma unroll
    for (int j = 0; j < 32; ++j) o += a2[j] * sow[j];
    out[(int)blockIdx.x * 32 + tid] = o;
  }
}

// ---------------- launch ----------------
extern "C" void kernel_launch(void* const* d_in, const int* in_sizes, int n_in,
                              void* d_out, int out_size, void* d_ws, size_t ws_size,
                              hipStream_t stream) {
  const float* f1   = (const float*)d_in[0];
  const float* f2   = (const float*)d_in[1];
  const float* ftw  = (const float*)d_in[2];
  const float* ftb  = (const float*)d_in[3];
  const float* h1w  = (const float*)d_in[4];
  const float* h1b  = (const float*)d_in[5];
  const float* h2w  = (const float*)d_in[6];
  const float* h2b  = (const float*)d_in[7];
  const float* outw = (const float*)d_in[8];
  const float* outb = (const float*)d_in[9];
  float* out = (float*)d_out;

  unsigned short* wb = (unsigned short*)d_ws;
  const size_t woff = (size_t)KHALF * FT_IN * 2;            // 21,004,288 B
  float* part = (float*)((char*)d_ws + woff);
  const size_t per = 2ull * KHALF * BATCH * 4;              // 16,777,216 B / kchunk

  // KS=4 -> 64rb x 2set x 4 = 512 WGs = exactly 2 WGs/CU (80 KB LDS), 1 round
  int KS = 1;
  if (ws_size >= woff + 4 * per)      KS = 4;
  else if (ws_size >= woff + 2 * per) KS = 2;

  wprep_kernel<<<2048, 256, 0, stream>>>(ftw, wb, (KHALF * FT_IN) / 4);
  ftgemm_kernel<<<dim3(64 * 2 * KS), 256, 0, stream>>>(f1, f2, wb, part, KS);
  tail_kernel<<<BATCH / 32, 256, 0, stream>>>(part, ftb, h1w, h1b, h2w, h2b,
                                              outw, outb, out, KS);
}

// Round 6
// 664.697 us; speedup vs baseline: 2.2471x; 1.0003x over previous
//
#include <hip/hip_runtime.h>
#include <stdint.h>
#include <stddef.h>

#define FT_IN 41024
#define KHALF 256
#define BATCH 8192
#define NKT 641          // 41024 / 64 K-tiles

typedef __attribute__((ext_vector_type(8))) short short8;
typedef __attribute__((ext_vector_type(4))) short short4v;
typedef __attribute__((ext_vector_type(4))) float f32x4;
typedef __attribute__((ext_vector_type(2))) uint32_t u32x2;

typedef const __attribute__((address_space(1))) uint32_t* gas1_t;
typedef __attribute__((address_space(3))) uint32_t* las3_t;

// fp32 -> bf16 RNE (bit trick) — used only in the small wprep pass
__device__ __forceinline__ unsigned short f2bf(float f) {
  union { float f; uint32_t u; } x; x.f = f;
  uint32_t u = x.u + 0x7FFFu + ((x.u >> 16) & 1u);
  return (unsigned short)(u >> 16);
}

#define MFMA16(acc, a, b) \
  asm("v_mfma_f32_16x16x32_bf16 %0, %1, %2, %0" : "+v"(acc) : "v"(a), "v"(b))

// packed fp32x2 -> bf16x2 (RNE), lo -> bits[15:0]
#define CVTPK(dst, lo, hi) \
  asm("v_cvt_pk_bf16_f32 %0, %1, %2" : "=v"(dst) : "v"(lo), "v"(hi))

// ---------------- kernel 1: ft_w fp32 -> bf16 ----------------
__global__ void wprep_kernel(const float* __restrict__ w,
                             unsigned short* __restrict__ o, int n4) {
  int i = blockIdx.x * blockDim.x + threadIdx.x;
  int stride = gridDim.x * blockDim.x;
  for (; i < n4; i += stride) {
    f32x4 v = ((const f32x4*)w)[i];
    short4v b;
    b.x = (short)f2bf(v.x); b.y = (short)f2bf(v.y);
    b.z = (short)f2bf(v.z); b.w = (short)f2bf(v.w);
    ((short4v*)o)[i] = b;
  }
}

// ---------------- kernel 2: feature-transform GEMM ----------------
// grid: 64 rowblocks x 2 sets x KS kchunks (512 WGs = 2/CU); block 256.
// per-WG tile: 128 rows x 256 cols (features read ONCE), BK=64.
// A: fp32 global -> v_cvt_pk_bf16 -> LDS (XOR-swizzled). W: bf16 global ->
// global_load_lds (source pre-swizzled), double-buffered (2x32KB).
// Pipeline: __syncthreads (drains the iteration-stale W(t) only) -> issue
// A(t+1)+W(t+1) -> MFMA -> RAW s_barrier (no vmcnt drain: prefetch stays in
// flight across the barrier and the cvt/ds_write phase). XCD-chunked bid
// swizzle puts one (st,ks) stream + one W slab per XCD (L2-resident window).
__global__ __launch_bounds__(256, 2) void ftgemm_kernel(
    const float* __restrict__ f1g, const float* __restrict__ f2g,
    const unsigned short* __restrict__ wb,
    float* __restrict__ part, int KS) {
  __shared__ alignas(16) char sA[16384];
  __shared__ alignas(16) char sW[2][32768];

  // XCD-aware chunked swizzle (nwg = 128*KS, divisible by 8 for KS in {1,2,4})
  const int nwg = (int)gridDim.x;
  const int orig = (int)blockIdx.x;
  int bid = (orig & 7) * (nwg >> 3) + (orig >> 3);

  const int rb = bid & 63; bid >>= 6;
  const int st = bid & 1;  bid >>= 1;
  const int ks = bid;

  const int kt0 = (ks * NKT) / KS;
  const int kt1 = ((ks + 1) * NKT) / KS;

  const int tid  = (int)threadIdx.x;
  const int lane = tid & 63;
  const int wv   = tid >> 6;
  const int wr   = (wv >> 1) << 6;   // wave row offset: 0 / 64
  const int wc   = (wv & 1) << 7;    // wave col offset: 0 / 128
  const int r16  = lane & 15;
  const int hi   = lane >> 4;

  const float* F = (st ? f2g : f1g) + (size_t)rb * (128ull * FT_IN);

  // A staging: thread covers rows (i*16 + tid>>4), k-chunk (tid&15)*4 floats
  const int arow = tid >> 4;
  const int akc  = tid & 15;
  const float* aptr = F + (size_t)arow * FT_IN + (size_t)kt0 * 64 + akc * 4;

  // W staging (global_load_lds, linear LDS dest): chunk c = i*256+tid,
  // row = c>>3 (i adds 32 rows), kc = c&7; source XOR-pre-swizzled.
  const int wrow = tid >> 3;
  const int wkc  = tid & 7;
  const int wkcs = wkc ^ (wrow & 7);
  const unsigned short* wptr =
      wb + (size_t)wrow * FT_IN + (size_t)kt0 * 64;

  f32x4 areg[8];
  f32x4 acc[4][8];
  const f32x4 fzero = {0.f, 0.f, 0.f, 0.f};
  #pragma unroll
  for (int m = 0; m < 4; ++m)
    #pragma unroll
    for (int n = 0; n < 8; ++n) acc[m][n] = fzero;

  // prologue: A regs + W glds for tile kt0
  #pragma unroll
  for (int i = 0; i < 8; ++i)
    areg[i] = *(const f32x4*)(aptr + (size_t)i * (16ull * FT_IN));
  #pragma unroll
  for (int i = 0; i < 8; ++i) {
    const unsigned short* g = wptr + (size_t)i * (32ull * FT_IN) + wkcs * 8;
    __builtin_amdgcn_global_load_lds((gas1_t)g,
        (las3_t)&sW[0][(i * 256 + tid) * 16], 16, 0, 0);
  }

  int buf = 0;
  for (int kt = kt0; kt < kt1; ++kt) {
    // phase A: cvt + store A tile (swizzle: byte ^= (row&7)<<4)
    // (compiler inserts the counted vmcnt wait for areg here)
    #pragma unroll
    for (int i = 0; i < 8; ++i) {
      const int row = i * 16 + arow;
      f32x4 v = areg[i];
      uint32_t b0, b1;
      CVTPK(b0, v.x, v.y);
      CVTPK(b1, v.z, v.w);
      u32x2 b; b.x = b0; b.y = b1;
      *(u32x2*)(sA + row * 128 + ((akc * 8) ^ ((row & 7) << 4))) = b;
    }
    // barrier 1: full drain — only W(t) (issued one iteration ago) is
    // outstanding here, so the vmcnt(0) is nearly free. Guarantees sA(t)
    // visible and all waves' W(t) glds landed in sW[buf].
    __syncthreads();

    // phase B: issue next tile's loads (stay in flight across barrier 2)
    if (kt + 1 < kt1) {
      const int d = kt + 1 - kt0;
      const float* ap = aptr + d * 64;
      #pragma unroll
      for (int i = 0; i < 8; ++i)
        areg[i] = *(const f32x4*)(ap + (size_t)i * (16ull * FT_IN));
      const unsigned short* wp = wptr + d * 64;
      #pragma unroll
      for (int i = 0; i < 8; ++i) {
        const unsigned short* g = wp + (size_t)i * (32ull * FT_IN) + wkcs * 8;
        __builtin_amdgcn_global_load_lds((gas1_t)g,
            (las3_t)&sW[buf ^ 1][(i * 256 + tid) * 16], 16, 0, 0);
      }
    }

    // phase C: MFMA
    const char* sWb = sW[buf];
    const int swz = (r16 & 7) << 4;
    #pragma unroll
    for (int k2 = 0; k2 < 2; ++k2) {
      const int ko = (k2 * 64 + hi * 16) ^ swz;
      short8 av[4], bv[8];
      #pragma unroll
      for (int m = 0; m < 4; ++m)
        av[m] = *(const short8*)(sA + (wr + m * 16 + r16) * 128 + ko);
      #pragma unroll
      for (int n = 0; n < 8; ++n)
        bv[n] = *(const short8*)(sWb + (wc + n * 16 + r16) * 128 + ko);
      #pragma unroll
      for (int m = 0; m < 4; ++m)
        #pragma unroll
        for (int n = 0; n < 8; ++n)
          MFMA16(acc[m][n], av[m], bv[n]);
    }

    // barrier 2: RAW s_barrier — no vmcnt drain; A(t+1)/W(t+1) stay in
    // flight through the next cvt/ds_write phase. All LDS reads of this
    // phase completed (consumed by MFMAs above), so no lgkm wait needed.
    __builtin_amdgcn_sched_barrier(0);
    __builtin_amdgcn_s_barrier();
    __builtin_amdgcn_sched_barrier(0);
    buf ^= 1;
  }

  // epilogue: raw partials [ks*2+set][col][row]; D frag: col = lane&15,
  // row = (lane>>4)*4 + reg (4 regs = 4 consecutive rows -> f32x4 store)
  float* pb = part + (size_t)(ks * 2 + st) * (KHALF * (size_t)BATCH);
  const int growb = rb * 128 + wr + hi * 4;
  const int gcolb = wc + r16;
  #pragma unroll
  for (int n = 0; n < 8; ++n)
    #pragma unroll
    for (int m = 0; m < 4; ++m)
      *(f32x4*)(pb + (size_t)(gcolb + n * 16) * BATCH + (growb + m * 16)) =
          acc[m][n];
}

// ---------------- kernel 3: tail MLP ----------------
// 256 blocks x 32 rows. Thread (r = tid&31, cg = tid>>5): row r, 64 cols
// [cg*64, cg*64+64). a1-partials reduced across the 8 col-groups via LDS.
__global__ __launch_bounds__(256) void tail_kernel(
    const float* __restrict__ part,
    const float* __restrict__ ftb, const float* __restrict__ h1w,
    const float* __restrict__ h1b, const float* __restrict__ h2w,
    const float* __restrict__ h2b, const float* __restrict__ outw,
    const float* __restrict__ outb, float* __restrict__ out, int KS) {
  __shared__ float sh1t[512 * 36];   // h1_w transposed [c][j], stride 36 (pad)
  __shared__ float sh2[32 * 32];
  __shared__ float sow[32];
  __shared__ float sh1b[32];
  __shared__ float sh2b[32];
  __shared__ float sftb[256];
  __shared__ float sob[1];

  const int tid = (int)threadIdx.x;
  // coalesced global read (c fast), strided LDS write
  for (int i = tid; i < 512 * 32; i += 256) {
    const int j = i >> 9, c = i & 511;
    sh1t[c * 36 + j] = h1w[i];       // h1w[j][c]
  }
  for (int i = tid; i < 1024; i += 256) sh2[i] = h2w[i];
  if (tid < 32) { sow[tid] = outw[tid]; sh1b[tid] = h1b[tid]; sh2b[tid] = h2b[tid]; }
  sftb[tid] = ftb[tid];
  if (tid == 0) sob[0] = outb[0];
  __syncthreads();

  const int r  = tid & 31;
  const int cg = tid >> 5;
  const int t  = (int)blockIdx.x * 32 + r;   // global batch row

  float a1p[32];
  #pragma unroll
  for (int j = 0; j < 32; ++j) a1p[j] = 0.f;

  for (int ci = 0; ci < 64; ++ci) {
    const int c   = cg * 64 + ci;
    const int set = c >> 8;
    const int cs  = c & 255;
    float v = sftb[cs];
    const float* p = part + ((size_t)set * KHALF + cs) * BATCH + t;
    for (int kq = 0; kq < KS; ++kq)
      v += p[(size_t)kq * (2ull * KHALF * BATCH)];
    v = fminf(fmaxf(v, 0.f), 1.f);
    const f32x4* wr4 = (const f32x4*)(sh1t + c * 36);
    #pragma unroll
    for (int q = 0; q < 8; ++q) {
      f32x4 wv = wr4[q];
      a1p[q * 4 + 0] += v * wv.x; a1p[q * 4 + 1] += v * wv.y;
      a1p[q * 4 + 2] += v * wv.z; a1p[q * 4 + 3] += v * wv.w;
    }
  }

  // reduce the 8 col-group partials per row via LDS (reuse sh1t region)
  float* red = sh1t;                  // [8][32][33]
  __syncthreads();
  #pragma unroll
  for (int j = 0; j < 32; ++j)
    red[(cg * 32 + r) * 33 + j] = a1p[j];
  __syncthreads();

  if (tid < 32) {
    float a1[32];
    #pragma unroll
    for (int j = 0; j < 32; ++j) a1[j] = sh1b[j];
    for (int g = 0; g < 8; ++g)
      #pragma unroll
      for (int j = 0; j < 32; ++j)
        a1[j] += red[(g * 32 + tid) * 33 + j];
    #pragma unroll
    for (int j = 0; j < 32; ++j) a1[j] = fminf(fmaxf(a1[j], 0.f), 1.f);

    float a2[32];
    #pragma unroll
    for (int j = 0; j < 32; ++j) {
      float x = sh2b[j];
      const f32x4* w2 = (const f32x4*)(sh2 + j * 32);
      #pragma unroll
      for (int q = 0; q < 8; ++q) {
        f32x4 wv = w2[q];
        x += a1[q * 4 + 0] * wv.x + a1[q * 4 + 1] * wv.y +
             a1[q * 4 + 2] * wv.z + a1[q * 4 + 3] * wv.w;
      }
      a2[j] = fminf(fmaxf(x, 0.f), 1.f);
    }
    float o = sob[0];
    #pragma unroll
    for (int j = 0; j < 32; ++j) o += a2[j] * sow[j];
    out[(int)blockIdx.x * 32 + tid] = o;
  }
}

// ---------------- launch ----------------
extern "C" void kernel_launch(void* const* d_in, const int* in_sizes, int n_in,
                              void* d_out, int out_size, void* d_ws, size_t ws_size,
                              hipStream_t stream) {
  const float* f1   = (const float*)d_in[0];
  const float* f2   = (const float*)d_in[1];
  const float* ftw  = (const float*)d_in[2];
  const float* ftb  = (const float*)d_in[3];
  const float* h1w  = (const float*)d_in[4];
  const float* h1b  = (const float*)d_in[5];
  const float* h2w  = (const float*)d_in[6];
  const float* h2b  = (const float*)d_in[7];
  const float* outw = (const float*)d_in[8];
  const float* outb = (const float*)d_in[9];
  float* out = (float*)d_out;

  unsigned short* wb = (unsigned short*)d_ws;
  const size_t woff = (size_t)KHALF * FT_IN * 2;            // 21,004,288 B
  float* part = (float*)((char*)d_ws + woff);
  const size_t per = 2ull * KHALF * BATCH * 4;              // 16,777,216 B / kchunk

  // KS=4 -> 64rb x 2set x 4 = 512 WGs = exactly 2 WGs/CU (80 KB LDS), 1 round
  int KS = 1;
  if (ws_size >= woff + 4 * per)      KS = 4;
  else if (ws_size >= woff + 2 * per) KS = 2;

  wprep_kernel<<<2048, 256, 0, stream>>>(ftw, wb, (KHALF * FT_IN) / 4);
  ftgemm_kernel<<<dim3(64 * 2 * KS), 256, 0, stream>>>(f1, f2, wb, part, KS);
  tail_kernel<<<BATCH / 32, 256, 0, stream>>>(part, ftb, h1w, h1b, h2w, h2b,
                                              outw, outb, out, KS);
}